// Round 3
// baseline (193.558 us; speedup 1.0000x reference)
//
#include <hip/hip_runtime.h>

#define NN 100000
#define NE 3200000
#define BSH 7                 // 128 nodes per bucket
#define BNODES 128
#define NBUCK 782             // ceil(NN/128)
#define BCAP 4800             // mean 4096, sigma 64 -> +11 sigma headroom
#define BIN_CHUNK 8192
#define NBIN_BLOCKS ((NE + BIN_CHUNK - 1) / BIN_CHUNK)   // 391 (last block: 5120 edges)
#define NL1_BLOCKS ((NN + 1023) / 1024)                  // 98 node-transform blocks
#define NAGG_BLOCKS 1568      // 98 groups x 16 (bucket x feature-half, XCD-paired)

#define S1 2097152.0f         // 2^21  layer-1 fixed-point scale
#define S2 524288.0f          // 2^19  layer-2 fixed-point scale
#define INV_S1 (1.0f / S1)
#define INV_S2 (1.0f / S2)

// ---------------- Fused: binning (blocks 0..NBIN_BLOCKS-1) + layer-1 node
// transform (trailing NL1_BLOCKS blocks). bucketCnt (+gsum) zeroed by
// hipMemsetAsync beforehand.
__global__ __launch_bounds__(1024, 8) void bin_and_l1(
        const float* __restrict__ x,
        const float* __restrict__ Wrel1,
        const float* __restrict__ brel1,
        const float* __restrict__ Wroot1,
        const int* __restrict__ src,
        const int* __restrict__ dst,
        int* __restrict__ y1q,
        int* __restrict__ initq,
        int* __restrict__ bucketCnt,
        int* __restrict__ bpay) {
    int t = threadIdx.x;

    if (blockIdx.x >= NBIN_BLOCKS) {
        // ---------------- node layer-1 role ----------------
        __shared__ float sW[16 * 8];
        __shared__ float sR[16 * 8];
        __shared__ float sb[8];
        if (t < 128) { sW[t] = Wrel1[t]; sR[t] = Wroot1[t]; }
        if (t < 8)   { sb[t] = brel1[t]; }
        __syncthreads();

        int i = (blockIdx.x - NBIN_BLOCKS) * 1024 + t;
        if (i >= NN) return;

        const float4* xp = (const float4*)(x + (size_t)i * 16);
        float4 x0 = xp[0], x1 = xp[1], x2 = xp[2], x3 = xp[3];
        float xi[16] = {x0.x, x0.y, x0.z, x0.w, x1.x, x1.y, x1.z, x1.w,
                        x2.x, x2.y, x2.z, x2.w, x3.x, x3.y, x3.z, x3.w};

        float y[8], r[8];
#pragma unroll
        for (int j = 0; j < 8; ++j) { y[j] = 0.0f; r[j] = sb[j]; }
#pragma unroll
        for (int k = 0; k < 16; ++k) {
            float xv = xi[k];
#pragma unroll
            for (int j = 0; j < 8; ++j) {
                y[j] = fmaf(xv, sW[k * 8 + j], y[j]);
                r[j] = fmaf(xv, sR[k * 8 + j], r[j]);
            }
        }
        int4* yp = (int4*)(y1q + (size_t)i * 8);
        int4* ap = (int4*)(initq + (size_t)i * 8);
        int4 q0, q1, p0, p1;
        q0.x = __float2int_rn(y[0] * S1); q0.y = __float2int_rn(y[1] * S1);
        q0.z = __float2int_rn(y[2] * S1); q0.w = __float2int_rn(y[3] * S1);
        q1.x = __float2int_rn(y[4] * S1); q1.y = __float2int_rn(y[5] * S1);
        q1.z = __float2int_rn(y[6] * S1); q1.w = __float2int_rn(y[7] * S1);
        p0.x = __float2int_rn(r[0] * S1); p0.y = __float2int_rn(r[1] * S1);
        p0.z = __float2int_rn(r[2] * S1); p0.w = __float2int_rn(r[3] * S1);
        p1.x = __float2int_rn(r[4] * S1); p1.y = __float2int_rn(r[5] * S1);
        p1.z = __float2int_rn(r[6] * S1); p1.w = __float2int_rn(r[7] * S1);
        yp[0] = q0; yp[1] = q1;
        ap[0] = p0; ap[1] = p1;
        return;
    }

    // ---------------- binning role ----------------
    __shared__ int2 stage2[BIN_CHUNK];   // (payload, global addr or -1): 64 KB
    __shared__ int  hist[NBUCK];         // histogram, then cursor
    __shared__ int  gdelta[NBUCK];       // b*BCAP + gbase_b - excl_b
    __shared__ int  wsum16[16];

    int e0 = blockIdx.x * BIN_CHUNK;
    int nE = NE - e0; if (nE > BIN_CHUNK) nE = BIN_CHUNK;
    int nv = nE >> 2;   // multiples of 4 always

    if (t < NBUCK) hist[t] = 0;
    __syncthreads();

    const int4* dst4 = (const int4*)(dst + e0);
    const int4* src4 = (const int4*)(src + e0);

    // phase 1: histogram; keep edges in registers (dst/src read once)
    int4 d0_, s0_, d1_, s1_;
    bool h0 = (t < nv), h1 = (t + 1024 < nv);
    if (h0) {
        d0_ = dst4[t]; s0_ = src4[t];
        atomicAdd(&hist[d0_.x >> BSH], 1);
        atomicAdd(&hist[d0_.y >> BSH], 1);
        atomicAdd(&hist[d0_.z >> BSH], 1);
        atomicAdd(&hist[d0_.w >> BSH], 1);
    }
    if (h1) {
        d1_ = dst4[t + 1024]; s1_ = src4[t + 1024];
        atomicAdd(&hist[d1_.x >> BSH], 1);
        atomicAdd(&hist[d1_.y >> BSH], 1);
        atomicAdd(&hist[d1_.z >> BSH], 1);
        atomicAdd(&hist[d1_.w >> BSH], 1);
    }
    __syncthreads();

    // phase 2: exclusive scan via wave shuffles (2 barriers total)
    int c = (t < NBUCK) ? hist[t] : 0;
    int lane = t & 63, w = t >> 6;
    int pref = c;
#pragma unroll
    for (int off = 1; off < 64; off <<= 1) {
        int u = __shfl_up(pref, off);
        if (lane >= off) pref += u;
    }
    if (lane == 63) wsum16[w] = pref;
    __syncthreads();
    if (t < 16) {
        int s = wsum16[t];
#pragma unroll
        for (int off = 1; off < 16; off <<= 1) {
            int u = __shfl_up(s, off);
            if (t >= off) s += u;
        }
        wsum16[t] = s;   // inclusive scan of wave sums
    }
    __syncthreads();
    int base = w ? wsum16[w - 1] : 0;
    int excl = base + pref - c;          // exclusive local offset for bucket t

    // phase 2b: reserve global space; hist becomes local cursor
    if (t < NBUCK) {
        int gb0 = c ? atomicAdd(&bucketCnt[t], c) : 0;
        hist[t] = excl;
        gdelta[t] = t * BCAP + gb0 - excl;
    }
    __syncthreads();

    // phase 3: bucket-sorted placement; store final global address alongside
#define PLACE1(dv, sv) do {                                              \
        int b_ = (dv) >> BSH;                                            \
        int r_ = atomicAdd(&hist[b_], 1);                                \
        int ga_ = r_ + gdelta[b_];                                       \
        int2 e_; e_.x = (((dv) & (BNODES - 1)) << 17) | (sv);            \
        e_.y = (ga_ < (b_ + 1) * BCAP) ? ga_ : -1;                       \
        stage2[r_] = e_;                                                 \
    } while (0)

    if (h0) { PLACE1(d0_.x, s0_.x); PLACE1(d0_.y, s0_.y);
              PLACE1(d0_.z, s0_.z); PLACE1(d0_.w, s0_.w); }
    if (h1) { PLACE1(d1_.x, s1_.x); PLACE1(d1_.y, s1_.y);
              PLACE1(d1_.z, s1_.z); PLACE1(d1_.w, s1_.w); }
#undef PLACE1
    __syncthreads();

    // phase 4: coalesced flush (no search -- address precomputed)
    for (int p = t; p < nE; p += 1024) {
        int2 e = stage2[p];
        if (e.y >= 0) bpay[e.y] = e.x;
    }
}

// ---------------- Bucket aggregation, layer 1, feature-half split ----------------
// Block = (bucket, feature-half). Each block fully owns 4 of 8 features of its
// 128 nodes, so the ReLU/quant epilogue stays local -- no cross-block merge.
// Block index interleave maps the two halves of a bucket to the SAME XCD so
// the second bpay read is an L2 hit.
__global__ __launch_bounds__(512, 8) void bucket_agg1(const int* __restrict__ bucketCnt,
                                                      const int* __restrict__ bpay,
                                                      const int* __restrict__ y1q,
                                                      int* __restrict__ h1q /* == initq */) {
    __shared__ int qacc[BNODES * 4];
    int t = threadIdx.x;
    int j = blockIdx.x & 15, kk = blockIdx.x >> 4;
    int b = (kk << 3) + (j & 7);
    int fh4 = (j >> 3) << 2;           // 0 or 4
    if (b >= NBUCK) return;
    int gb = b * BCAP;
    int fbase = b * (BNODES * 8);

    {   // init: qacc[node*4 + f] = initq[node, fh4+f]
        int node = t >> 2, f = t & 3;
        int gi = fbase + node * 8 + fh4 + f;
        qacc[t] = (gi < NN * 8) ? h1q[gi] : 0;
    }
    int C = bucketCnt[b]; if (C > BCAP) C = BCAP;
    __syncthreads();

    int f = t & 3, g = t >> 2;   // 128 groups x 4 feature lanes
    const int4* bp4 = (const int4*)(bpay + gb);
    int iters = C >> 10;          // 1024 edges per iteration
    for (int it = 0; it < iters; ++it) {
        int4 va = bp4[(it << 8) + (g << 1)];
        int4 vb = bp4[(it << 8) + (g << 1) + 1];
        int a0 = y1q[((va.x & 0x1FFFF) << 3) + fh4 + f];
        int a1 = y1q[((va.y & 0x1FFFF) << 3) + fh4 + f];
        int a2 = y1q[((va.z & 0x1FFFF) << 3) + fh4 + f];
        int a3 = y1q[((va.w & 0x1FFFF) << 3) + fh4 + f];
        int a4 = y1q[((vb.x & 0x1FFFF) << 3) + fh4 + f];
        int a5 = y1q[((vb.y & 0x1FFFF) << 3) + fh4 + f];
        int a6 = y1q[((vb.z & 0x1FFFF) << 3) + fh4 + f];
        int a7 = y1q[((vb.w & 0x1FFFF) << 3) + fh4 + f];
        atomicAdd(&qacc[((va.x >> 17) << 2) + f], a0);
        atomicAdd(&qacc[((va.y >> 17) << 2) + f], a1);
        atomicAdd(&qacc[((va.z >> 17) << 2) + f], a2);
        atomicAdd(&qacc[((va.w >> 17) << 2) + f], a3);
        atomicAdd(&qacc[((vb.x >> 17) << 2) + f], a4);
        atomicAdd(&qacc[((vb.y >> 17) << 2) + f], a5);
        atomicAdd(&qacc[((vb.z >> 17) << 2) + f], a6);
        atomicAdd(&qacc[((vb.w >> 17) << 2) + f], a7);
    }
    for (int e = (iters << 10) + g; e < C; e += 128) {
        int v = bpay[gb + e];
        int a = y1q[((v & 0x1FFFF) << 3) + fh4 + f];
        atomicAdd(&qacc[((v >> 17) << 2) + f], a);
    }
    __syncthreads();

    {   // epilogue: relu + requantize, write owned features in place
        int node = t >> 2, fo = t & 3;
        int gi = fbase + node * 8 + fh4 + fo;
        if (gi < NN * 8) {
            float h = (float)qacc[t] * INV_S1;
            h = h > 0.0f ? h : 0.0f;
            h1q[gi] = __float2int_rn(h * S2);
        }
    }
}

// ---------------- Bucket aggregation, layer 2, feature-half split ----------------
// Stores raw int sums to sagg (plain stores; kernel boundary gives coherence).
// sagg ALIASES y1q: y1q is dead after bucket_agg1 (agg2 gathers from h1q only),
// so no extra workspace beyond the round-1 footprint is used.
__global__ __launch_bounds__(512, 8) void bucket_agg2(const int* __restrict__ bucketCnt,
                                                      const int* __restrict__ bpay,
                                                      const int* __restrict__ h1q,
                                                      int* __restrict__ sagg) {
    __shared__ int qacc[BNODES * 4];
    int t = threadIdx.x;
    int j = blockIdx.x & 15, kk = blockIdx.x >> 4;
    int b = (kk << 3) + (j & 7);
    int fh4 = (j >> 3) << 2;
    if (b >= NBUCK) return;
    int gb = b * BCAP;
    int fbase = b * (BNODES * 8);

    qacc[t] = 0;
    int C = bucketCnt[b]; if (C > BCAP) C = BCAP;
    __syncthreads();

    int f = t & 3, g = t >> 2;
    const int4* bp4 = (const int4*)(bpay + gb);
    int iters = C >> 10;
    for (int it = 0; it < iters; ++it) {
        int4 va = bp4[(it << 8) + (g << 1)];
        int4 vb = bp4[(it << 8) + (g << 1) + 1];
        int a0 = h1q[((va.x & 0x1FFFF) << 3) + fh4 + f];   // already relu'd, S2-scaled
        int a1 = h1q[((va.y & 0x1FFFF) << 3) + fh4 + f];
        int a2 = h1q[((va.z & 0x1FFFF) << 3) + fh4 + f];
        int a3 = h1q[((va.w & 0x1FFFF) << 3) + fh4 + f];
        int a4 = h1q[((vb.x & 0x1FFFF) << 3) + fh4 + f];
        int a5 = h1q[((vb.y & 0x1FFFF) << 3) + fh4 + f];
        int a6 = h1q[((vb.z & 0x1FFFF) << 3) + fh4 + f];
        int a7 = h1q[((vb.w & 0x1FFFF) << 3) + fh4 + f];
        atomicAdd(&qacc[((va.x >> 17) << 2) + f], a0);
        atomicAdd(&qacc[((va.y >> 17) << 2) + f], a1);
        atomicAdd(&qacc[((va.z >> 17) << 2) + f], a2);
        atomicAdd(&qacc[((va.w >> 17) << 2) + f], a3);
        atomicAdd(&qacc[((vb.x >> 17) << 2) + f], a4);
        atomicAdd(&qacc[((vb.y >> 17) << 2) + f], a5);
        atomicAdd(&qacc[((vb.z >> 17) << 2) + f], a6);
        atomicAdd(&qacc[((vb.w >> 17) << 2) + f], a7);
    }
    for (int e = (iters << 10) + g; e < C; e += 128) {
        int v = bpay[gb + e];
        int a = h1q[((v & 0x1FFFF) << 3) + fh4 + f];
        atomicAdd(&qacc[((v >> 17) << 2) + f], a);
    }
    __syncthreads();

    {   // store owned aggregated sums (raw S2-scaled ints)
        int node = t >> 2, fo = t & 3;
        int gi = fbase + node * 8 + fh4 + fo;
        if (gi < NN * 8) sagg[gi] = qacc[t];
    }
}

// ---------------- Dense tail: GraphConv2 linear + fc1 + fc2, node-parallel ----------------
__global__ __launch_bounds__(512) void dense_tail(const int* __restrict__ h1q,
                                                  const int* __restrict__ sagg,
                                                  const float* __restrict__ Wrel2,
                                                  const float* __restrict__ brel2,
                                                  const float* __restrict__ Wroot2,
                                                  const float* __restrict__ Wfc1,
                                                  const float* __restrict__ bfc1,
                                                  const float* __restrict__ Wfc2,
                                                  const float* __restrict__ bfc2,
                                                  float* __restrict__ out,
                                                  float* __restrict__ gsum) {
    __shared__ float sWrel2[128], sWroot2[128], sbrel2[16];
    __shared__ float sWfc1[512], sbfc1[32], sWfc2[32];
    __shared__ float sbfc2;
    __shared__ float wsum[8];

    int t = threadIdx.x;
    sWfc1[t] = Wfc1[t];
    if (t < 128) { sWrel2[t] = Wrel2[t]; sWroot2[t] = Wroot2[t]; }
    if (t >= 128 && t < 144) sbrel2[t - 128] = brel2[t - 128];
    if (t >= 192 && t < 224) { sbfc1[t - 192] = bfc1[t - 192]; sWfc2[t - 192] = Wfc2[t - 192]; }
    if (t == 256) sbfc2 = bfc2[0];
    __syncthreads();

    int node = blockIdx.x * 512 + t;
    float o = 0.0f;
    if (node < NN) {
        const int4* hp = (const int4*)(h1q + (size_t)node * 8);
        const int4* sp = (const int4*)(sagg + (size_t)node * 8);
        int4 ha = hp[0], hb = hp[1];
        int4 sa = sp[0], sb = sp[1];
        float h1v[8] = {ha.x * INV_S2, ha.y * INV_S2, ha.z * INV_S2, ha.w * INV_S2,
                        hb.x * INV_S2, hb.y * INV_S2, hb.z * INV_S2, hb.w * INV_S2};
        float s2[8]  = {sa.x * INV_S2, sa.y * INV_S2, sa.z * INV_S2, sa.w * INV_S2,
                        sb.x * INV_S2, sb.y * INV_S2, sb.z * INV_S2, sb.w * INV_S2};

        float h2[16];
#pragma unroll
        for (int jj = 0; jj < 16; ++jj) h2[jj] = sbrel2[jj];
#pragma unroll
        for (int k = 0; k < 8; ++k) {
            float sv = s2[k], hv = h1v[k];
#pragma unroll
            for (int jj = 0; jj < 16; ++jj) {
                h2[jj] = fmaf(sv, sWrel2[k * 16 + jj], h2[jj]);
                h2[jj] = fmaf(hv, sWroot2[k * 16 + jj], h2[jj]);
            }
        }
#pragma unroll
        for (int jj = 0; jj < 16; ++jj) h2[jj] = h2[jj] > 0.0f ? h2[jj] : 0.0f;

        o = sbfc2;
#pragma unroll
        for (int m = 0; m < 32; ++m) {
            float a = sbfc1[m];
#pragma unroll
            for (int jj = 0; jj < 16; ++jj) a = fmaf(h2[jj], sWfc1[jj * 32 + m], a);
            a = a > 0.0f ? a : 0.0f;
            o = fmaf(a, sWfc2[m], o);
        }
        out[node] = o;
    }

    float v = o;
#pragma unroll
    for (int off = 32; off > 0; off >>= 1) v += __shfl_down(v, off);
    int lane = t & 63, w = t >> 6;
    if (lane == 0) wsum[w] = v;
    __syncthreads();
    if (t == 0) {
        float s = 0.0f;
#pragma unroll
        for (int k = 0; k < 8; ++k) s += wsum[k];
        atomicAdd(gsum, s);
    }
}

__global__ void subtract_mean(float* __restrict__ out,
                              const float* __restrict__ gsum) {
    int i = blockIdx.x * blockDim.x + threadIdx.x;
    if (i < NN) out[i] -= (*gsum) * (1.0f / (float)NN);
}

extern "C" void kernel_launch(void* const* d_in, const int* in_sizes, int n_in,
                              void* d_out, int out_size, void* d_ws, size_t ws_size,
                              hipStream_t stream) {
    const float* x      = (const float*)d_in[0];
    const int*   ei     = (const int*)d_in[1];
    const float* Wrel1  = (const float*)d_in[2];
    const float* brel1  = (const float*)d_in[3];
    const float* Wroot1 = (const float*)d_in[4];
    const float* Wrel2  = (const float*)d_in[5];
    const float* brel2  = (const float*)d_in[6];
    const float* Wroot2 = (const float*)d_in[7];
    const float* Wfc1   = (const float*)d_in[8];
    const float* bfc1   = (const float*)d_in[9];
    const float* Wfc2   = (const float*)d_in[10];
    const float* bfc2   = (const float*)d_in[11];
    float* out = (float*)d_out;
    float* ws  = (float*)d_ws;

    // workspace layout (4-byte units) -- identical footprint to round 1
    int*   y1q       = (int*)ws;                  // 800000
    int*   h1q       = (int*)(ws + 800000);       // 800000 (initq -> h1q in place)
    int*   bucketCnt = (int*)(ws + 1600000);      // 782 (+1 gsum)
    float* gsum      = ws + 1600782;              // 1
    int*   bpay      = (int*)(ws + 1600783);      // 782*4800 = 3753600 (ends 5354383)
    int*   sagg      = y1q;                       // ALIAS: y1q dead after bucket_agg1

    const int* src = ei;
    const int* dst = ei + NE;

    hipMemsetAsync(bucketCnt, 0, (NBUCK + 1) * sizeof(int), stream);  // counts + gsum
    bin_and_l1<<<NBIN_BLOCKS + NL1_BLOCKS, 1024, 0, stream>>>(x, Wrel1, brel1, Wroot1,
                                                              src, dst, y1q, h1q,
                                                              bucketCnt, bpay);
    bucket_agg1<<<NAGG_BLOCKS, 512, 0, stream>>>(bucketCnt, bpay, y1q, h1q);
    bucket_agg2<<<NAGG_BLOCKS, 512, 0, stream>>>(bucketCnt, bpay, h1q, sagg);
    dense_tail<<<(NN + 511) / 512, 512, 0, stream>>>(h1q, sagg,
                                                     Wrel2, brel2, Wroot2,
                                                     Wfc1, bfc1, Wfc2, bfc2, out, gsum);
    subtract_mean<<<(NN + 255) / 256, 256, 0, stream>>>(out, gsum);
}

// Round 4
// 167.885 us; speedup vs baseline: 1.1529x; 1.1529x over previous
//
#include <hip/hip_runtime.h>

#define NN 100000
#define NE 3200000
#define BSH 7                 // 128 nodes per bucket
#define BNODES 128
#define NBUCK 782             // ceil(NN/128)
#define BCAP 4800             // mean 4096, sigma 64 -> +11 sigma headroom
#define BIN_CHUNK 8192
#define NBIN_BLOCKS ((NE + BIN_CHUNK - 1) / BIN_CHUNK)   // 391 (last block: 5120 edges)
#define NL1_BLOCKS ((NN + 1023) / 1024)                  // 98 node-transform blocks

#define S1 2097152.0f         // 2^21  layer-1 fixed-point scale
#define S2 524288.0f          // 2^19  layer-2 fixed-point scale
#define INV_S1 (1.0f / S1)
#define INV_S2 (1.0f / S2)

// ---------------- Fused: binning (blocks 0..NBIN_BLOCKS-1) + layer-1 node
// transform (trailing NL1_BLOCKS blocks). bucketCnt (+gsum) zeroed by
// hipMemsetAsync beforehand.
__global__ __launch_bounds__(1024, 8) void bin_and_l1(
        const float* __restrict__ x,
        const float* __restrict__ Wrel1,
        const float* __restrict__ brel1,
        const float* __restrict__ Wroot1,
        const int* __restrict__ src,
        const int* __restrict__ dst,
        int* __restrict__ y1q,
        int* __restrict__ initq,
        int* __restrict__ bucketCnt,
        int* __restrict__ bpay) {
    int t = threadIdx.x;

    if (blockIdx.x >= NBIN_BLOCKS) {
        // ---------------- node layer-1 role ----------------
        __shared__ float sW[16 * 8];
        __shared__ float sR[16 * 8];
        __shared__ float sb[8];
        if (t < 128) { sW[t] = Wrel1[t]; sR[t] = Wroot1[t]; }
        if (t < 8)   { sb[t] = brel1[t]; }
        __syncthreads();

        int i = (blockIdx.x - NBIN_BLOCKS) * 1024 + t;
        if (i >= NN) return;

        const float4* xp = (const float4*)(x + (size_t)i * 16);
        float4 x0 = xp[0], x1 = xp[1], x2 = xp[2], x3 = xp[3];
        float xi[16] = {x0.x, x0.y, x0.z, x0.w, x1.x, x1.y, x1.z, x1.w,
                        x2.x, x2.y, x2.z, x2.w, x3.x, x3.y, x3.z, x3.w};

        float y[8], r[8];
#pragma unroll
        for (int j = 0; j < 8; ++j) { y[j] = 0.0f; r[j] = sb[j]; }
#pragma unroll
        for (int k = 0; k < 16; ++k) {
            float xv = xi[k];
#pragma unroll
            for (int j = 0; j < 8; ++j) {
                y[j] = fmaf(xv, sW[k * 8 + j], y[j]);
                r[j] = fmaf(xv, sR[k * 8 + j], r[j]);
            }
        }
        int4* yp = (int4*)(y1q + (size_t)i * 8);
        int4* ap = (int4*)(initq + (size_t)i * 8);
        int4 q0, q1, p0, p1;
        q0.x = __float2int_rn(y[0] * S1); q0.y = __float2int_rn(y[1] * S1);
        q0.z = __float2int_rn(y[2] * S1); q0.w = __float2int_rn(y[3] * S1);
        q1.x = __float2int_rn(y[4] * S1); q1.y = __float2int_rn(y[5] * S1);
        q1.z = __float2int_rn(y[6] * S1); q1.w = __float2int_rn(y[7] * S1);
        p0.x = __float2int_rn(r[0] * S1); p0.y = __float2int_rn(r[1] * S1);
        p0.z = __float2int_rn(r[2] * S1); p0.w = __float2int_rn(r[3] * S1);
        p1.x = __float2int_rn(r[4] * S1); p1.y = __float2int_rn(r[5] * S1);
        p1.z = __float2int_rn(r[6] * S1); p1.w = __float2int_rn(r[7] * S1);
        yp[0] = q0; yp[1] = q1;
        ap[0] = p0; ap[1] = p1;
        return;
    }

    // ---------------- binning role ----------------
    __shared__ int2 stage2[BIN_CHUNK];   // (payload, global addr or -1): 64 KB
    __shared__ int  hist[NBUCK];         // histogram, then cursor
    __shared__ int  gdelta[NBUCK];       // b*BCAP + gbase_b - excl_b
    __shared__ int  wsum16[16];

    int e0 = blockIdx.x * BIN_CHUNK;
    int nE = NE - e0; if (nE > BIN_CHUNK) nE = BIN_CHUNK;
    int nv = nE >> 2;   // multiples of 4 always

    if (t < NBUCK) hist[t] = 0;
    __syncthreads();

    const int4* dst4 = (const int4*)(dst + e0);
    const int4* src4 = (const int4*)(src + e0);

    // phase 1: histogram; keep edges in registers (dst/src read once)
    int4 d0_, s0_, d1_, s1_;
    bool h0 = (t < nv), h1 = (t + 1024 < nv);
    if (h0) {
        d0_ = dst4[t]; s0_ = src4[t];
        atomicAdd(&hist[d0_.x >> BSH], 1);
        atomicAdd(&hist[d0_.y >> BSH], 1);
        atomicAdd(&hist[d0_.z >> BSH], 1);
        atomicAdd(&hist[d0_.w >> BSH], 1);
    }
    if (h1) {
        d1_ = dst4[t + 1024]; s1_ = src4[t + 1024];
        atomicAdd(&hist[d1_.x >> BSH], 1);
        atomicAdd(&hist[d1_.y >> BSH], 1);
        atomicAdd(&hist[d1_.z >> BSH], 1);
        atomicAdd(&hist[d1_.w >> BSH], 1);
    }
    __syncthreads();

    // phase 2: exclusive scan via wave shuffles (2 barriers total)
    int c = (t < NBUCK) ? hist[t] : 0;
    int lane = t & 63, w = t >> 6;
    int pref = c;
#pragma unroll
    for (int off = 1; off < 64; off <<= 1) {
        int u = __shfl_up(pref, off);
        if (lane >= off) pref += u;
    }
    if (lane == 63) wsum16[w] = pref;
    __syncthreads();
    if (t < 16) {
        int s = wsum16[t];
#pragma unroll
        for (int off = 1; off < 16; off <<= 1) {
            int u = __shfl_up(s, off);
            if (t >= off) s += u;
        }
        wsum16[t] = s;   // inclusive scan of wave sums
    }
    __syncthreads();
    int base = w ? wsum16[w - 1] : 0;
    int excl = base + pref - c;          // exclusive local offset for bucket t

    // phase 2b: reserve global space; hist becomes local cursor
    if (t < NBUCK) {
        int gb0 = c ? atomicAdd(&bucketCnt[t], c) : 0;
        hist[t] = excl;
        gdelta[t] = t * BCAP + gb0 - excl;
    }
    __syncthreads();

    // phase 3: bucket-sorted placement; store final global address alongside
#define PLACE1(dv, sv) do {                                              \
        int b_ = (dv) >> BSH;                                            \
        int r_ = atomicAdd(&hist[b_], 1);                                \
        int ga_ = r_ + gdelta[b_];                                       \
        int2 e_; e_.x = (((dv) & (BNODES - 1)) << 17) | (sv);            \
        e_.y = (ga_ < (b_ + 1) * BCAP) ? ga_ : -1;                       \
        stage2[r_] = e_;                                                 \
    } while (0)

    if (h0) { PLACE1(d0_.x, s0_.x); PLACE1(d0_.y, s0_.y);
              PLACE1(d0_.z, s0_.z); PLACE1(d0_.w, s0_.w); }
    if (h1) { PLACE1(d1_.x, s1_.x); PLACE1(d1_.y, s1_.y);
              PLACE1(d1_.z, s1_.z); PLACE1(d1_.w, s1_.w); }
#undef PLACE1
    __syncthreads();

    // phase 4: coalesced flush (no search -- address precomputed)
    for (int p = t; p < nE; p += 1024) {
        int2 e = stage2[p];
        if (e.y >= 0) bpay[e.y] = e.x;
    }
}

// ---------------- Bucket aggregation, layer 1 (x2-unrolled gather loop) ----------------
// h1q[n] = round(S2 * relu( (initq[n] + sum_{j->n} y1q[j]) / S1 ))   (in place over initq)
// Inner loop processes 16 edges/thread: 16 gathers issued before 16 LDS
// atomics -> 2x the outstanding loads per thread vs round-1 (latency hiding).
__global__ __launch_bounds__(512, 8) void bucket_agg1(const int* __restrict__ bucketCnt,
                                                      const int* __restrict__ bpay,
                                                      const int* __restrict__ y1q,
                                                      int* __restrict__ h1q /* == initq */) {
    __shared__ int qacc[BNODES * 8];
    int t = threadIdx.x;
    int b = blockIdx.x;
    int gb = b * BCAP;
    int fbase = b * (BNODES * 8);

    for (int k = t; k < BNODES * 8; k += 512) {
        int gi = fbase + k;
        qacc[k] = (gi < NN * 8) ? h1q[gi] : 0;
    }
    int C = bucketCnt[b]; if (C > BCAP) C = BCAP;
    __syncthreads();

    int f = t & 7, g = t >> 3;   // 64 groups x 8 feature lanes
    const int4* bp4 = (const int4*)(bpay + gb);
    int iters = C >> 10;          // 1024 edges per iteration (16 per thread)
    for (int it = 0; it < iters; ++it) {
        int4 va = bp4[(it << 8) + (g << 2)];
        int4 vb = bp4[(it << 8) + (g << 2) + 1];
        int4 vc = bp4[(it << 8) + (g << 2) + 2];
        int4 vd = bp4[(it << 8) + (g << 2) + 3];
        int a0 = y1q[((va.x & 0x1FFFF) << 3) + f];
        int a1 = y1q[((va.y & 0x1FFFF) << 3) + f];
        int a2 = y1q[((va.z & 0x1FFFF) << 3) + f];
        int a3 = y1q[((va.w & 0x1FFFF) << 3) + f];
        int a4 = y1q[((vb.x & 0x1FFFF) << 3) + f];
        int a5 = y1q[((vb.y & 0x1FFFF) << 3) + f];
        int a6 = y1q[((vb.z & 0x1FFFF) << 3) + f];
        int a7 = y1q[((vb.w & 0x1FFFF) << 3) + f];
        int a8 = y1q[((vc.x & 0x1FFFF) << 3) + f];
        int a9 = y1q[((vc.y & 0x1FFFF) << 3) + f];
        int aa = y1q[((vc.z & 0x1FFFF) << 3) + f];
        int ab = y1q[((vc.w & 0x1FFFF) << 3) + f];
        int ac = y1q[((vd.x & 0x1FFFF) << 3) + f];
        int ad = y1q[((vd.y & 0x1FFFF) << 3) + f];
        int ae = y1q[((vd.z & 0x1FFFF) << 3) + f];
        int af = y1q[((vd.w & 0x1FFFF) << 3) + f];
        atomicAdd(&qacc[((va.x >> 17) << 3) + f], a0);
        atomicAdd(&qacc[((va.y >> 17) << 3) + f], a1);
        atomicAdd(&qacc[((va.z >> 17) << 3) + f], a2);
        atomicAdd(&qacc[((va.w >> 17) << 3) + f], a3);
        atomicAdd(&qacc[((vb.x >> 17) << 3) + f], a4);
        atomicAdd(&qacc[((vb.y >> 17) << 3) + f], a5);
        atomicAdd(&qacc[((vb.z >> 17) << 3) + f], a6);
        atomicAdd(&qacc[((vb.w >> 17) << 3) + f], a7);
        atomicAdd(&qacc[((vc.x >> 17) << 3) + f], a8);
        atomicAdd(&qacc[((vc.y >> 17) << 3) + f], a9);
        atomicAdd(&qacc[((vc.z >> 17) << 3) + f], aa);
        atomicAdd(&qacc[((vc.w >> 17) << 3) + f], ab);
        atomicAdd(&qacc[((vd.x >> 17) << 3) + f], ac);
        atomicAdd(&qacc[((vd.y >> 17) << 3) + f], ad);
        atomicAdd(&qacc[((vd.z >> 17) << 3) + f], ae);
        atomicAdd(&qacc[((vd.w >> 17) << 3) + f], af);
    }
    for (int e = (iters << 10) + g; e < C; e += 64) {
        int v = bpay[gb + e];
        int a = y1q[((v & 0x1FFFF) << 3) + f];
        atomicAdd(&qacc[((v >> 17) << 3) + f], a);
    }
    __syncthreads();

    for (int k = t; k < BNODES * 8; k += 512) {
        int gi = fbase + k;
        if (gi < NN * 8) {
            float h = (float)qacc[k] * INV_S1;
            h = h > 0.0f ? h : 0.0f;
            h1q[gi] = __float2int_rn(h * S2);
        }
    }
}

// ---------------- Bucket aggregation layer 2 + fused dense tail (x2-unrolled) ----------------
__global__ __launch_bounds__(512, 6) void bucket_agg2_tail(const int* __restrict__ bucketCnt,
                                                           const int* __restrict__ bpay,
                                                           const int* __restrict__ h1q,
                                                           const float* __restrict__ Wrel2,
                                                           const float* __restrict__ brel2,
                                                           const float* __restrict__ Wroot2,
                                                           const float* __restrict__ Wfc1,
                                                           const float* __restrict__ bfc1,
                                                           const float* __restrict__ Wfc2,
                                                           const float* __restrict__ bfc2,
                                                           float* __restrict__ out,
                                                           float* __restrict__ gsum) {
    __shared__ int qacc[BNODES * 8];
    __shared__ float sWrel2[128], sWroot2[128], sbrel2[16];
    __shared__ float sWfc1[512], sbfc1[32], sWfc2[32];
    __shared__ float sbfc2;
    __shared__ float wsum[8];

    int t = threadIdx.x;
    int b = blockIdx.x;
    int gb = b * BCAP;
    int n0 = b * BNODES;

    for (int k = t; k < BNODES * 8; k += 512) qacc[k] = 0;
    sWfc1[t] = Wfc1[t];
    if (t < 128) { sWrel2[t] = Wrel2[t]; sWroot2[t] = Wroot2[t]; }
    if (t >= 128 && t < 144) sbrel2[t - 128] = brel2[t - 128];
    if (t >= 192 && t < 224) { sbfc1[t - 192] = bfc1[t - 192]; sWfc2[t - 192] = Wfc2[t - 192]; }
    if (t == 256) sbfc2 = bfc2[0];
    int C = bucketCnt[b]; if (C > BCAP) C = BCAP;
    __syncthreads();

    int f = t & 7, g = t >> 3;
    const int4* bp4 = (const int4*)(bpay + gb);
    int iters = C >> 10;          // 1024 edges per iteration (16 per thread)
    for (int it = 0; it < iters; ++it) {
        int4 va = bp4[(it << 8) + (g << 2)];
        int4 vb = bp4[(it << 8) + (g << 2) + 1];
        int4 vc = bp4[(it << 8) + (g << 2) + 2];
        int4 vd = bp4[(it << 8) + (g << 2) + 3];
        int a0 = h1q[((va.x & 0x1FFFF) << 3) + f];   // already relu'd, S2-scaled
        int a1 = h1q[((va.y & 0x1FFFF) << 3) + f];
        int a2 = h1q[((va.z & 0x1FFFF) << 3) + f];
        int a3 = h1q[((va.w & 0x1FFFF) << 3) + f];
        int a4 = h1q[((vb.x & 0x1FFFF) << 3) + f];
        int a5 = h1q[((vb.y & 0x1FFFF) << 3) + f];
        int a6 = h1q[((vb.z & 0x1FFFF) << 3) + f];
        int a7 = h1q[((vb.w & 0x1FFFF) << 3) + f];
        int a8 = h1q[((vc.x & 0x1FFFF) << 3) + f];
        int a9 = h1q[((vc.y & 0x1FFFF) << 3) + f];
        int aa = h1q[((vc.z & 0x1FFFF) << 3) + f];
        int ab = h1q[((vc.w & 0x1FFFF) << 3) + f];
        int ac = h1q[((vd.x & 0x1FFFF) << 3) + f];
        int ad = h1q[((vd.y & 0x1FFFF) << 3) + f];
        int ae = h1q[((vd.z & 0x1FFFF) << 3) + f];
        int af = h1q[((vd.w & 0x1FFFF) << 3) + f];
        atomicAdd(&qacc[((va.x >> 17) << 3) + f], a0);
        atomicAdd(&qacc[((va.y >> 17) << 3) + f], a1);
        atomicAdd(&qacc[((va.z >> 17) << 3) + f], a2);
        atomicAdd(&qacc[((va.w >> 17) << 3) + f], a3);
        atomicAdd(&qacc[((vb.x >> 17) << 3) + f], a4);
        atomicAdd(&qacc[((vb.y >> 17) << 3) + f], a5);
        atomicAdd(&qacc[((vb.z >> 17) << 3) + f], a6);
        atomicAdd(&qacc[((vb.w >> 17) << 3) + f], a7);
        atomicAdd(&qacc[((vc.x >> 17) << 3) + f], a8);
        atomicAdd(&qacc[((vc.y >> 17) << 3) + f], a9);
        atomicAdd(&qacc[((vc.z >> 17) << 3) + f], aa);
        atomicAdd(&qacc[((vc.w >> 17) << 3) + f], ab);
        atomicAdd(&qacc[((vd.x >> 17) << 3) + f], ac);
        atomicAdd(&qacc[((vd.y >> 17) << 3) + f], ad);
        atomicAdd(&qacc[((vd.z >> 17) << 3) + f], ae);
        atomicAdd(&qacc[((vd.w >> 17) << 3) + f], af);
    }
    for (int e = (iters << 10) + g; e < C; e += 64) {
        int v = bpay[gb + e];
        int a = h1q[((v & 0x1FFFF) << 3) + f];
        atomicAdd(&qacc[((v >> 17) << 3) + f], a);
    }
    __syncthreads();

    float o = 0.0f;
    int node = n0 + t;
    if (t < BNODES && node < NN) {
        const int4* hp = (const int4*)(h1q + (size_t)node * 8);
        int4 ha = hp[0], hb = hp[1];
        float h1v[8] = {ha.x * INV_S2, ha.y * INV_S2, ha.z * INV_S2, ha.w * INV_S2,
                        hb.x * INV_S2, hb.y * INV_S2, hb.z * INV_S2, hb.w * INV_S2};
        float s2[8];
#pragma unroll
        for (int j = 0; j < 8; ++j) s2[j] = (float)qacc[t * 8 + j] * INV_S2;

        float h2[16];
#pragma unroll
        for (int j = 0; j < 16; ++j) h2[j] = sbrel2[j];
#pragma unroll
        for (int k = 0; k < 8; ++k) {
            float sv = s2[k], hv = h1v[k];
#pragma unroll
            for (int j = 0; j < 16; ++j) {
                h2[j] = fmaf(sv, sWrel2[k * 16 + j], h2[j]);
                h2[j] = fmaf(hv, sWroot2[k * 16 + j], h2[j]);
            }
        }
#pragma unroll
        for (int j = 0; j < 16; ++j) h2[j] = h2[j] > 0.0f ? h2[j] : 0.0f;

        o = sbfc2;
#pragma unroll
        for (int m = 0; m < 32; ++m) {
            float a = sbfc1[m];
#pragma unroll
            for (int j = 0; j < 16; ++j) a = fmaf(h2[j], sWfc1[j * 32 + m], a);
            a = a > 0.0f ? a : 0.0f;
            o = fmaf(a, sWfc2[m], o);
        }
        out[node] = o;
    }

    float v = o;
#pragma unroll
    for (int off = 32; off > 0; off >>= 1) v += __shfl_down(v, off);
    int lane = t & 63, w = t >> 6;
    if (lane == 0) wsum[w] = v;
    __syncthreads();
    if (t == 0) {
        float s = 0.0f;
#pragma unroll
        for (int k = 0; k < 8; ++k) s += wsum[k];
        atomicAdd(gsum, s);
    }
}

__global__ void subtract_mean(float* __restrict__ out,
                              const float* __restrict__ gsum) {
    int i = blockIdx.x * blockDim.x + threadIdx.x;
    if (i < NN) out[i] -= (*gsum) * (1.0f / (float)NN);
}

extern "C" void kernel_launch(void* const* d_in, const int* in_sizes, int n_in,
                              void* d_out, int out_size, void* d_ws, size_t ws_size,
                              hipStream_t stream) {
    const float* x      = (const float*)d_in[0];
    const int*   ei     = (const int*)d_in[1];
    const float* Wrel1  = (const float*)d_in[2];
    const float* brel1  = (const float*)d_in[3];
    const float* Wroot1 = (const float*)d_in[4];
    const float* Wrel2  = (const float*)d_in[5];
    const float* brel2  = (const float*)d_in[6];
    const float* Wroot2 = (const float*)d_in[7];
    const float* Wfc1   = (const float*)d_in[8];
    const float* bfc1   = (const float*)d_in[9];
    const float* Wfc2   = (const float*)d_in[10];
    const float* bfc2   = (const float*)d_in[11];
    float* out = (float*)d_out;
    float* ws  = (float*)d_ws;

    // workspace layout (4-byte units) -- identical footprint to round 1
    int*   y1q       = (int*)ws;                  // 800000
    int*   h1q       = (int*)(ws + 800000);       // 800000 (initq -> h1q in place)
    int*   bucketCnt = (int*)(ws + 1600000);      // 782 (+1 gsum)
    float* gsum      = ws + 1600782;              // 1
    int*   bpay      = (int*)(ws + 1600783);      // 782*4800 = 3753600 (ends 5354383)

    const int* src = ei;
    const int* dst = ei + NE;

    hipMemsetAsync(bucketCnt, 0, (NBUCK + 1) * sizeof(int), stream);  // counts + gsum
    bin_and_l1<<<NBIN_BLOCKS + NL1_BLOCKS, 1024, 0, stream>>>(x, Wrel1, brel1, Wroot1,
                                                              src, dst, y1q, h1q,
                                                              bucketCnt, bpay);
    bucket_agg1<<<NBUCK, 512, 0, stream>>>(bucketCnt, bpay, y1q, h1q);
    bucket_agg2_tail<<<NBUCK, 512, 0, stream>>>(bucketCnt, bpay, h1q,
                                                Wrel2, brel2, Wroot2,
                                                Wfc1, bfc1, Wfc2, bfc2, out, gsum);
    subtract_mean<<<(NN + 255) / 256, 256, 0, stream>>>(out, gsum);
}